// Round 2
// baseline (762.299 us; speedup 1.0000x reference)
//
#include <hip/hip_runtime.h>
#include <hip/hip_bf16.h>

#define NN 50000
#define NE 600000
#define DIM 128
#define NG 64

using bf16x8 = __attribute__((ext_vector_type(8))) __bf16;
using f32x4  = __attribute__((ext_vector_type(4))) float;

// convert 8 contiguous fp32 -> bf16x8 (two vec4 loads + pack cvt)
__device__ __forceinline__ bf16x8 cvt8(const float* __restrict__ p) {
    f32x4 a = *(const f32x4*)p;
    f32x4 b = *(const f32x4*)(p + 4);
    bf16x8 r;
    #pragma unroll
    for (int i = 0; i < 4; ++i) { r[i] = (__bf16)a[i]; r[i + 4] = (__bf16)b[i]; }
    return r;
}

// ---------------------------------------------------------------------------
// Stage W[128][128] fp32 -> bf16 LDS with 136-elem row stride (breaks 256B
// power-of-2 stride; <=2-way bank conflicts are free per m136).
// ---------------------------------------------------------------------------
__device__ __forceinline__ void stage_weights(const float* __restrict__ W, __bf16* sW) {
    for (int i = threadIdx.x; i < 128 * 16; i += 256) {   // 2048 chunks of 8
        int row = i >> 4, seg = i & 15;
        *(bf16x8*)(&sW[row * 136 + seg * 8]) = cvt8(W + row * 128 + seg * 8);
    }
    __syncthreads();
}

// ---------------------------------------------------------------------------
// Y[M][128] = X[M][128] @ W[128][128]^T + bias   (fp32 in, fp32 out,
// bf16 MFMA core). One wave = 16-row x 128-col tile, 32 mfma_16x16x32_bf16.
// A-frag: A[m=lane&15][k=quad*8+j]; B-frag: B[n=lane&15][k=quad*8+j];
// C/D: row=quad*4+reg, col=lane&15  (verified layouts, m89/m120).
// ---------------------------------------------------------------------------
__global__ __launch_bounds__(256) void gemm_bias(
    const float* __restrict__ X, const float* __restrict__ W,
    const float* __restrict__ bias, float* __restrict__ Y, int M)
{
    __shared__ __bf16 sW[128 * 136];
    stage_weights(W, sW);

    int wave = threadIdx.x >> 6, lane = threadIdx.x & 63;
    int col = lane & 15, quad = lane >> 4;
    int tile = (blockIdx.x * 4 + wave) * 16;
    if (tile >= M) return;

    f32x4 acc[8] = {};
    const float* xp = X + (size_t)(tile + col) * DIM + quad * 8;
    #pragma unroll
    for (int k0 = 0; k0 < 128; k0 += 32) {
        bf16x8 a = cvt8(xp + k0);
        #pragma unroll
        for (int t = 0; t < 8; ++t) {
            bf16x8 b = *(const bf16x8*)(&sW[(t * 16 + col) * 136 + k0 + quad * 8]);
            acc[t] = __builtin_amdgcn_mfma_f32_16x16x32_bf16(a, b, acc[t], 0, 0, 0);
        }
    }

    float bv[8];
    #pragma unroll
    for (int t = 0; t < 8; ++t) bv[t] = bias[t * 16 + col];
    #pragma unroll
    for (int r = 0; r < 4; ++r) {
        float* yp = Y + (size_t)(tile + quad * 4 + r) * DIM;
        #pragma unroll
        for (int t = 0; t < 8; ++t) yp[t * 16 + col] = acc[t][r] + bv[t];
    }
}

// ---------------------------------------------------------------------------
// Edge kernel: msg = silu(h[src] + edge_attr @ we^T + be); atomicAdd to agg[dst].
// ---------------------------------------------------------------------------
__global__ __launch_bounds__(256) void edge_msg(
    const float* __restrict__ EA, const float* __restrict__ W,
    const float* __restrict__ bias,
    const int* __restrict__ src, const int* __restrict__ dst,
    const float* __restrict__ H, float* __restrict__ AGG)
{
    __shared__ __bf16 sW[128 * 136];
    stage_weights(W, sW);

    int wave = threadIdx.x >> 6, lane = threadIdx.x & 63;
    int col = lane & 15, quad = lane >> 4;
    int tile = (blockIdx.x * 4 + wave) * 16;  // NE=600000=16*37500; 37500=4*9375 -> always full

    f32x4 acc[8] = {};
    const float* xp = EA + (size_t)(tile + col) * DIM + quad * 8;
    #pragma unroll
    for (int k0 = 0; k0 < 128; k0 += 32) {
        bf16x8 a = cvt8(xp + k0);
        #pragma unroll
        for (int t = 0; t < 8; ++t) {
            bf16x8 b = *(const bf16x8*)(&sW[(t * 16 + col) * 136 + k0 + quad * 8]);
            acc[t] = __builtin_amdgcn_mfma_f32_16x16x32_bf16(a, b, acc[t], 0, 0, 0);
        }
    }

    float bv[8];
    #pragma unroll
    for (int t = 0; t < 8; ++t) bv[t] = bias[t * 16 + col];

    #pragma unroll
    for (int r = 0; r < 4; ++r) {
        int e = tile + quad * 4 + r;
        int s  = src[e];
        int dd = dst[e];
        const float* hp = H + (size_t)s * DIM;
        float* ap = AGG + (size_t)dd * DIM;
        #pragma unroll
        for (int t = 0; t < 8; ++t) {
            int d = t * 16 + col;
            float v = acc[t][r] + bv[t] + hp[d];
            v = v / (1.f + __expf(-v));        // SiLU
            atomicAdd(&ap[d], v);
        }
    }
}

// ---------------------------------------------------------------------------
// x = silu((1+eps)*h + agg) + node_h  (in-place over H);
// per-(graph,dim) sums + counts via sorted-batch run accumulation.
// Block: 128 threads (thread = dim), 64 nodes per block.
// ---------------------------------------------------------------------------
__global__ __launch_bounds__(128) void fuse_x_stats(
    float* __restrict__ H, const float* __restrict__ AGG,
    const float* __restrict__ node_h, const float* __restrict__ epsp,
    const int* __restrict__ batch,
    float* __restrict__ SUMS, float* __restrict__ CNT, int M)
{
    int d = threadIdx.x;
    int n0 = blockIdx.x * 64;
    int nend = min(n0 + 64, M);
    float epsv = 1.f + epsp[0];

    int cur_g = batch[n0];
    float run = 0.f; int runlen = 0;
    for (int n = n0; n < nend; ++n) {
        int g = batch[n];
        if (g != cur_g) {
            atomicAdd(&SUMS[cur_g * DIM + d], run);
            if (d == 0) atomicAdd(&CNT[cur_g], (float)runlen);
            run = 0.f; runlen = 0; cur_g = g;
        }
        size_t idx = (size_t)n * DIM + d;
        float v = epsv * H[idx] + AGG[idx];
        v = v / (1.f + __expf(-v));
        v += node_h[idx];
        H[idx] = v;                  // x overwrites h (h dead after this)
        run += v; runlen++;
    }
    atomicAdd(&SUMS[cur_g * DIM + d], run);
    if (d == 0) atomicAdd(&CNT[cur_g], (float)runlen);
}

// ---------------------------------------------------------------------------
// var accumulation: sum over nodes of (x - mean*mean_scale)^2 per (graph,dim)
// ---------------------------------------------------------------------------
__global__ __launch_bounds__(128) void var_pass(
    const float* __restrict__ X, const int* __restrict__ batch,
    const float* __restrict__ msc,
    const float* __restrict__ SUMS, const float* __restrict__ CNT,
    float* __restrict__ VARS, int M)
{
    int d = threadIdx.x;
    int n0 = blockIdx.x * 64;
    int nend = min(n0 + 64, M);
    float ms = msc[d];

    int cur_g = batch[n0];
    float c = fmaxf(CNT[cur_g], 1.f);
    float mean = SUMS[cur_g * DIM + d] / c;
    float run = 0.f;
    for (int n = n0; n < nend; ++n) {
        int g = batch[n];
        if (g != cur_g) {
            atomicAdd(&VARS[cur_g * DIM + d], run);
            run = 0.f; cur_g = g;
            c = fmaxf(CNT[g], 1.f);
            mean = SUMS[g * DIM + d] / c;
        }
        float v = X[(size_t)n * DIM + d] - mean * ms;
        run += v * v;
    }
    atomicAdd(&VARS[cur_g * DIM + d], run);
}

// ---------------------------------------------------------------------------
// out = weight*(x - mean*ms)/sqrt(var/cnt + 1e-5) + bias   (fp32 out)
// ---------------------------------------------------------------------------
__global__ __launch_bounds__(128) void finalize(
    const float* __restrict__ X, const int* __restrict__ batch,
    const float* __restrict__ msc,
    const float* __restrict__ SUMS, const float* __restrict__ VARS,
    const float* __restrict__ CNT,
    const float* __restrict__ gw, const float* __restrict__ gb,
    float* __restrict__ OUT, int M)
{
    int d = threadIdx.x;
    int n0 = blockIdx.x * 64;
    int nend = min(n0 + 64, M);
    float ms = msc[d];
    float wd = gw[d];
    float bd = gb[d];

    int cur_g = -1;
    float mean = 0.f, rstd = 0.f;
    for (int n = n0; n < nend; ++n) {
        int g = batch[n];
        if (g != cur_g) {
            cur_g = g;
            float c = fmaxf(CNT[g], 1.f);
            mean = SUMS[g * DIM + d] / c;
            rstd = rsqrtf(VARS[g * DIM + d] / c + 1e-5f);
        }
        size_t idx = (size_t)n * DIM + d;
        float v = X[idx] - mean * ms;
        OUT[idx] = wd * v * rstd + bd;
    }
}

// ---------------------------------------------------------------------------
extern "C" void kernel_launch(void* const* d_in, const int* in_sizes, int n_in,
                              void* d_out, int out_size, void* d_ws, size_t ws_size,
                              hipStream_t stream) {
    const float* node_h    = (const float*)d_in[0];
    const float* edge_attr = (const float*)d_in[1];
    const int*   batch     = (const int*)d_in[2];
    const int*   eidx      = (const int*)d_in[3];   // [2][NE]: src row, dst row
    const float* w1        = (const float*)d_in[4];
    const float* b1        = (const float*)d_in[5];
    const float* we        = (const float*)d_in[6];
    const float* be        = (const float*)d_in[7];
    const float* eps       = (const float*)d_in[8];
    const float* gnw       = (const float*)d_in[9];
    const float* gnb       = (const float*)d_in[10];
    const float* gnms      = (const float*)d_in[11];

    float* ws   = (float*)d_ws;
    float* H    = ws;                       // N*D fp32 (h, then x in-place)
    float* AGG  = ws + 6400000;             // N*D fp32
    float* SUMS = ws + 12800000;            // G*D
    float* VARS = SUMS + NG * DIM;          // G*D
    float* CNT  = VARS + NG * DIM;          // G

    // zero agg + sums + vars + cnt in one shot (contiguous)
    hipMemsetAsync(AGG, 0, (size_t)(6400000 + NG * DIM * 2 + NG) * sizeof(float), stream);

    gemm_bias<<<782, 256, 0, stream>>>(node_h, w1, b1, H, NN);   // 3125 tiles / 4 waves
    edge_msg<<<9375, 256, 0, stream>>>(edge_attr, we, be, eidx, eidx + NE, H, AGG);
    fuse_x_stats<<<782, 128, 0, stream>>>(H, AGG, node_h, eps, batch, SUMS, CNT, NN);
    var_pass<<<782, 128, 0, stream>>>(H, batch, gnms, SUMS, CNT, VARS, NN);
    finalize<<<782, 128, 0, stream>>>(H, batch, gnms, SUMS, VARS, CNT, gnw, gnb,
                                      (float*)d_out, NN);
}

// Round 3
// 724.697 us; speedup vs baseline: 1.0519x; 1.0519x over previous
//
#include <hip/hip_runtime.h>
#include <hip/hip_bf16.h>

#define NN 50000
#define NE 600000
#define DIM 128
#define NG 64
#define NCHUNK 98           // ceil(50000/512)

using bf16x8 = __attribute__((ext_vector_type(8))) __bf16;
using f32x4  = __attribute__((ext_vector_type(4))) float;

// convert 8 contiguous fp32 -> bf16x8
__device__ __forceinline__ bf16x8 cvt8(const float* __restrict__ p) {
    f32x4 a = *(const f32x4*)p;
    f32x4 b = *(const f32x4*)(p + 4);
    bf16x8 r;
    #pragma unroll
    for (int i = 0; i < 4; ++i) { r[i] = (__bf16)a[i]; r[i + 4] = (__bf16)b[i]; }
    return r;
}

// Stage W[128][128] fp32 -> bf16 LDS, 136-elem row stride (no 4+-way conflicts)
__device__ __forceinline__ void stage_weights(const float* __restrict__ W, __bf16* sW) {
    for (int i = threadIdx.x; i < 128 * 16; i += 256) {
        int row = i >> 4, seg = i & 15;
        *(bf16x8*)(&sW[row * 136 + seg * 8]) = cvt8(W + row * 128 + seg * 8);
    }
    __syncthreads();
}

// ---------------------------------------------------------------------------
// H = node_h @ w1^T + b1  (fp32 in/out, bf16 MFMA core)
// ---------------------------------------------------------------------------
__global__ __launch_bounds__(256) void gemm_bias(
    const float* __restrict__ X, const float* __restrict__ W,
    const float* __restrict__ bias, float* __restrict__ Y, int M)
{
    __shared__ __bf16 sW[128 * 136];
    stage_weights(W, sW);

    int wave = threadIdx.x >> 6, lane = threadIdx.x & 63;
    int col = lane & 15, quad = lane >> 4;
    int tile = (blockIdx.x * 4 + wave) * 16;
    if (tile >= M) return;

    f32x4 acc[8] = {};
    const float* xp = X + (size_t)(tile + col) * DIM + quad * 8;
    #pragma unroll
    for (int k0 = 0; k0 < 128; k0 += 32) {
        bf16x8 a = cvt8(xp + k0);
        #pragma unroll
        for (int t = 0; t < 8; ++t) {
            bf16x8 b = *(const bf16x8*)(&sW[(t * 16 + col) * 136 + k0 + quad * 8]);
            acc[t] = __builtin_amdgcn_mfma_f32_16x16x32_bf16(a, b, acc[t], 0, 0, 0);
        }
    }
    float bv[8];
    #pragma unroll
    for (int t = 0; t < 8; ++t) bv[t] = bias[t * 16 + col];
    #pragma unroll
    for (int r = 0; r < 4; ++r) {
        float* yp = Y + (size_t)(tile + quad * 4 + r) * DIM;
        #pragma unroll
        for (int t = 0; t < 8; ++t) yp[t * 16 + col] = acc[t][r] + bv[t];
    }
}

// ===========================================================================
// CSR build: histogram -> 3-stage exclusive scan -> slot assignment
// ===========================================================================
__global__ __launch_bounds__(256) void k_hist(const int* __restrict__ dst, int* __restrict__ deg) {
    int e = blockIdx.x * 256 + threadIdx.x;
    if (e < NE) atomicAdd(&deg[dst[e]], 1);
}

__global__ __launch_bounds__(256) void k_scan_a(const int* __restrict__ deg, int* __restrict__ chunkSum) {
    __shared__ int s[256];
    int c = blockIdx.x, t = threadIdx.x;
    int b = c * 512 + t;
    int v = (b < NN) ? deg[b] : 0;
    if (b + 256 < NN) v += deg[b + 256];
    s[t] = v; __syncthreads();
    for (int off = 128; off > 0; off >>= 1) {
        if (t < off) s[t] += s[t + off];
        __syncthreads();
    }
    if (t == 0) chunkSum[c] = s[0];
}

__global__ __launch_bounds__(128) void k_scan_b(const int* __restrict__ chunkSum,
                                                int* __restrict__ chunkOff, int* __restrict__ rowptr) {
    __shared__ int s[128];
    int t = threadIdx.x;
    int v = (t < NCHUNK) ? chunkSum[t] : 0;
    s[t] = v; __syncthreads();
    for (int off = 1; off < 128; off <<= 1) {
        int x = (t >= off) ? s[t - off] : 0;
        __syncthreads();
        s[t] += x;
        __syncthreads();
    }
    chunkOff[t] = s[t] - v;           // exclusive
    if (t == 0) rowptr[NN] = NE;
}

__global__ __launch_bounds__(512) void k_scan_c(const int* __restrict__ deg,
                                                const int* __restrict__ chunkOff,
                                                int* __restrict__ rowptr, int* __restrict__ pos) {
    __shared__ int s[512];
    int c = blockIdx.x, t = threadIdx.x;
    int i = c * 512 + t;
    int v = (i < NN) ? deg[i] : 0;
    s[t] = v; __syncthreads();
    for (int off = 1; off < 512; off <<= 1) {
        int x = (t >= off) ? s[t - off] : 0;
        __syncthreads();
        s[t] += x;
        __syncthreads();
    }
    if (i < NN) { rowptr[i] = chunkOff[c] + s[t] - v; pos[i] = 0; }
}

__global__ __launch_bounds__(256) void k_slot(const int* __restrict__ dst,
                                              const int* __restrict__ rowptr,
                                              int* __restrict__ pos, int* __restrict__ slot) {
    int e = blockIdx.x * 256 + threadIdx.x;
    if (e >= NE) return;
    int d = dst[e];
    int p = atomicAdd(&pos[d], 1);
    slot[e] = rowptr[d] + p;
}

// ---------------------------------------------------------------------------
// Edge GEMM: msg = silu(h[src] + ea @ we^T + be), stored bf16 at dst-sorted
// slot. No atomics.
// ---------------------------------------------------------------------------
__global__ __launch_bounds__(256) void edge_msg_sorted(
    const float* __restrict__ EA, const float* __restrict__ W,
    const float* __restrict__ bias,
    const int* __restrict__ src, const int* __restrict__ slot,
    const float* __restrict__ H, __hip_bfloat16* __restrict__ MSG)
{
    __shared__ __bf16 sW[128 * 136];
    stage_weights(W, sW);

    int wave = threadIdx.x >> 6, lane = threadIdx.x & 63;
    int col = lane & 15, quad = lane >> 4;
    int tile = (blockIdx.x * 4 + wave) * 16;   // NE = 16*37500 = 4*9375*16: always full

    f32x4 acc[8] = {};
    const float* xp = EA + (size_t)(tile + col) * DIM + quad * 8;
    #pragma unroll
    for (int k0 = 0; k0 < 128; k0 += 32) {
        bf16x8 a = cvt8(xp + k0);
        #pragma unroll
        for (int t = 0; t < 8; ++t) {
            bf16x8 b = *(const bf16x8*)(&sW[(t * 16 + col) * 136 + k0 + quad * 8]);
            acc[t] = __builtin_amdgcn_mfma_f32_16x16x32_bf16(a, b, acc[t], 0, 0, 0);
        }
    }
    float bv[8];
    #pragma unroll
    for (int t = 0; t < 8; ++t) bv[t] = bias[t * 16 + col];

    #pragma unroll
    for (int r = 0; r < 4; ++r) {
        int e = tile + quad * 4 + r;
        int s  = src[e];
        int sl = slot[e];
        const float* hp = H + (size_t)s * DIM;
        __hip_bfloat16* mp = MSG + (size_t)sl * DIM;
        #pragma unroll
        for (int t = 0; t < 8; ++t) {
            int d = t * 16 + col;
            float v = acc[t][r] + bv[t] + hp[d];
            v = v / (1.f + __expf(-v));        // SiLU
            mp[d] = __float2bfloat16(v);
        }
    }
}

// ---------------------------------------------------------------------------
// Per-node gather of contiguous msg slots + x = silu((1+eps)h + agg) + node_h
// (in-place over H). One 128-thread block per node, thread = dim.
// ---------------------------------------------------------------------------
__global__ __launch_bounds__(128) void k_gather(
    const __hip_bfloat16* __restrict__ MSG, const int* __restrict__ rowptr,
    float* __restrict__ H, const float* __restrict__ node_h,
    const float* __restrict__ epsp)
{
    int n = blockIdx.x, d = threadIdx.x;
    int s = rowptr[n], epos = rowptr[n + 1];
    float acc = 0.f;
    for (int e = s; e < epos; ++e)
        acc += __bfloat162float(MSG[(size_t)e * DIM + d]);
    size_t idx = (size_t)n * DIM + d;
    float v = (1.f + epsp[0]) * H[idx] + acc;
    v = v / (1.f + __expf(-v));
    H[idx] = v + node_h[idx];
}

// ===========================================================================
// GraphNorm passes (shared by both paths). 16 nodes / 128-thread block.
// ===========================================================================
__global__ __launch_bounds__(128) void stats_pass(
    const float* __restrict__ X, const int* __restrict__ batch,
    float* __restrict__ SUMS, float* __restrict__ CNT, int npb)
{
    int d = threadIdx.x;
    int n0 = blockIdx.x * npb;
    int nend = min(n0 + npb, NN);
    if (n0 >= NN) return;
    int cur_g = batch[n0];
    float run = 0.f; int runlen = 0;
    for (int n = n0; n < nend; ++n) {
        int g = batch[n];
        if (g != cur_g) {
            atomicAdd(&SUMS[cur_g * DIM + d], run);
            if (d == 0) atomicAdd(&CNT[cur_g], (float)runlen);
            run = 0.f; runlen = 0; cur_g = g;
        }
        run += X[(size_t)n * DIM + d]; runlen++;
    }
    atomicAdd(&SUMS[cur_g * DIM + d], run);
    if (d == 0) atomicAdd(&CNT[cur_g], (float)runlen);
}

__global__ __launch_bounds__(128) void var_pass(
    const float* __restrict__ X, const int* __restrict__ batch,
    const float* __restrict__ msc,
    const float* __restrict__ SUMS, const float* __restrict__ CNT,
    float* __restrict__ VARS, int npb)
{
    int d = threadIdx.x;
    int n0 = blockIdx.x * npb;
    int nend = min(n0 + npb, NN);
    if (n0 >= NN) return;
    float ms = msc[d];
    int cur_g = batch[n0];
    float c = fmaxf(CNT[cur_g], 1.f);
    float mean = SUMS[cur_g * DIM + d] / c;
    float run = 0.f;
    for (int n = n0; n < nend; ++n) {
        int g = batch[n];
        if (g != cur_g) {
            atomicAdd(&VARS[cur_g * DIM + d], run);
            run = 0.f; cur_g = g;
            c = fmaxf(CNT[g], 1.f);
            mean = SUMS[g * DIM + d] / c;
        }
        float v = X[(size_t)n * DIM + d] - mean * ms;
        run += v * v;
    }
    atomicAdd(&VARS[cur_g * DIM + d], run);
}

__global__ __launch_bounds__(128) void finalize(
    const float* __restrict__ X, const int* __restrict__ batch,
    const float* __restrict__ msc,
    const float* __restrict__ SUMS, const float* __restrict__ VARS,
    const float* __restrict__ CNT,
    const float* __restrict__ gw, const float* __restrict__ gb,
    float* __restrict__ OUT, int npb)
{
    int d = threadIdx.x;
    int n0 = blockIdx.x * npb;
    int nend = min(n0 + npb, NN);
    if (n0 >= NN) return;
    float ms = msc[d], wd = gw[d], bd = gb[d];
    int cur_g = -1;
    float mean = 0.f, rstd = 0.f;
    for (int n = n0; n < nend; ++n) {
        int g = batch[n];
        if (g != cur_g) {
            cur_g = g;
            float c = fmaxf(CNT[g], 1.f);
            mean = SUMS[g * DIM + d] / c;
            rstd = rsqrtf(VARS[g * DIM + d] / c + 1e-5f);
        }
        size_t idx = (size_t)n * DIM + d;
        float v = X[idx] - mean * ms;
        OUT[idx] = wd * v * rstd + bd;
    }
}

// ===========================================================================
// Fallback path kernels (atomic scatter, as Round-2) if ws is too small
// ===========================================================================
__global__ __launch_bounds__(256) void edge_msg_atomic(
    const float* __restrict__ EA, const float* __restrict__ W,
    const float* __restrict__ bias,
    const int* __restrict__ src, const int* __restrict__ dst,
    const float* __restrict__ H, float* __restrict__ AGG)
{
    __shared__ __bf16 sW[128 * 136];
    stage_weights(W, sW);
    int wave = threadIdx.x >> 6, lane = threadIdx.x & 63;
    int col = lane & 15, quad = lane >> 4;
    int tile = (blockIdx.x * 4 + wave) * 16;
    f32x4 acc[8] = {};
    const float* xp = EA + (size_t)(tile + col) * DIM + quad * 8;
    #pragma unroll
    for (int k0 = 0; k0 < 128; k0 += 32) {
        bf16x8 a = cvt8(xp + k0);
        #pragma unroll
        for (int t = 0; t < 8; ++t) {
            bf16x8 b = *(const bf16x8*)(&sW[(t * 16 + col) * 136 + k0 + quad * 8]);
            acc[t] = __builtin_amdgcn_mfma_f32_16x16x32_bf16(a, b, acc[t], 0, 0, 0);
        }
    }
    float bv[8];
    #pragma unroll
    for (int t = 0; t < 8; ++t) bv[t] = bias[t * 16 + col];
    #pragma unroll
    for (int r = 0; r < 4; ++r) {
        int e = tile + quad * 4 + r;
        int s = src[e], dd = dst[e];
        const float* hp = H + (size_t)s * DIM;
        float* ap = AGG + (size_t)dd * DIM;
        #pragma unroll
        for (int t = 0; t < 8; ++t) {
            int d = t * 16 + col;
            float v = acc[t][r] + bv[t] + hp[d];
            v = v / (1.f + __expf(-v));
            atomicAdd(&ap[d], v);
        }
    }
}

__global__ __launch_bounds__(128) void fuse_x_atomic(
    float* __restrict__ H, const float* __restrict__ AGG,
    const float* __restrict__ node_h, const float* __restrict__ epsp, int npb)
{
    int d = threadIdx.x;
    int n0 = blockIdx.x * npb;
    int nend = min(n0 + npb, NN);
    if (n0 >= NN) return;
    float epsv = 1.f + epsp[0];
    for (int n = n0; n < nend; ++n) {
        size_t idx = (size_t)n * DIM + d;
        float v = epsv * H[idx] + AGG[idx];
        v = v / (1.f + __expf(-v));
        H[idx] = v + node_h[idx];
    }
}

// ===========================================================================
extern "C" void kernel_launch(void* const* d_in, const int* in_sizes, int n_in,
                              void* d_out, int out_size, void* d_ws, size_t ws_size,
                              hipStream_t stream) {
    const float* node_h    = (const float*)d_in[0];
    const float* edge_attr = (const float*)d_in[1];
    const int*   batch     = (const int*)d_in[2];
    const int*   eidx      = (const int*)d_in[3];   // [2][NE]: src, dst
    const float* w1        = (const float*)d_in[4];
    const float* b1        = (const float*)d_in[5];
    const float* we        = (const float*)d_in[6];
    const float* be        = (const float*)d_in[7];
    const float* eps       = (const float*)d_in[8];
    const float* gnw       = (const float*)d_in[9];
    const float* gnb       = (const float*)d_in[10];
    const float* gnms      = (const float*)d_in[11];
    const int* src = eidx, * dst = eidx + NE;

    char* base = (char*)d_ws;
    float* H = (float*)base;                                    // 25.6 MB

    // fast-path layout (bytes)
    size_t oMSG   = 25600000;                                   // bf16 [E][128] = 153.6 MB
    size_t oROW   = oMSG + 153600000;                           // int [NN+1]
    size_t oDEG   = oROW + 200064;                              // int [NN]   (also pos)
    size_t oSUMS  = oDEG + 200000;                              // f [G*D]
    size_t oVARS  = oSUMS + 32768;
    size_t oCNT   = oVARS + 32768;
    size_t oSLOT  = oCNT + 256;                                 // int [NE]
    size_t oCSA   = oSLOT + 2400000;                            // chunkSum int[128]
    size_t oCSB   = oCSA + 512;                                 // chunkOff int[128]
    size_t needed = oCSB + 512;

    bool fast = ws_size >= needed;

    if (fast) {
        __hip_bfloat16* MSG = (__hip_bfloat16*)(base + oMSG);
        int* rowptr = (int*)(base + oROW);
        int* deg    = (int*)(base + oDEG);
        float* SUMS = (float*)(base + oSUMS);
        float* VARS = (float*)(base + oVARS);
        float* CNT  = (float*)(base + oCNT);
        int* slot   = (int*)(base + oSLOT);
        int* csum   = (int*)(base + oCSA);
        int* coff   = (int*)(base + oCSB);

        // zero deg + SUMS + VARS + CNT (contiguous)
        hipMemsetAsync(deg, 0, 200000 + 32768 + 32768 + 256, stream);

        gemm_bias<<<782, 256, 0, stream>>>(node_h, w1, b1, H, NN);
        k_hist  <<<(NE + 255) / 256, 256, 0, stream>>>(dst, deg);
        k_scan_a<<<NCHUNK, 256, 0, stream>>>(deg, csum);
        k_scan_b<<<1, 128, 0, stream>>>(csum, coff, rowptr);
        k_scan_c<<<NCHUNK, 512, 0, stream>>>(deg, coff, rowptr, deg /*pos, zeroed in-kernel*/);
        k_slot  <<<(NE + 255) / 256, 256, 0, stream>>>(dst, rowptr, deg, slot);
        edge_msg_sorted<<<9375, 256, 0, stream>>>(edge_attr, we, be, src, slot, H, MSG);
        k_gather<<<NN, 128, 0, stream>>>(MSG, rowptr, H, node_h, eps);
        stats_pass<<<3125, 128, 0, stream>>>(H, batch, SUMS, CNT, 16);
        var_pass  <<<3125, 128, 0, stream>>>(H, batch, gnms, SUMS, CNT, VARS, 16);
        finalize  <<<3125, 128, 0, stream>>>(H, batch, gnms, SUMS, VARS, CNT, gnw, gnb,
                                             (float*)d_out, 16);
    } else {
        // fallback: Round-2 atomic path (ws >= ~51.3 MB known to exist)
        float* AGG  = H + 6400000;
        float* SUMS = H + 12800000;
        float* VARS = SUMS + NG * DIM;
        float* CNT  = VARS + NG * DIM;
        hipMemsetAsync(AGG, 0, (size_t)(6400000 + NG * DIM * 2 + NG) * sizeof(float), stream);
        gemm_bias<<<782, 256, 0, stream>>>(node_h, w1, b1, H, NN);
        edge_msg_atomic<<<9375, 256, 0, stream>>>(edge_attr, we, be, src, dst, H, AGG);
        fuse_x_atomic<<<3125, 128, 0, stream>>>(H, AGG, node_h, eps, 16);
        stats_pass<<<3125, 128, 0, stream>>>(H, batch, SUMS, CNT, 16);
        var_pass  <<<3125, 128, 0, stream>>>(H, batch, gnms, SUMS, CNT, VARS, 16);
        finalize  <<<3125, 128, 0, stream>>>(H, batch, gnms, SUMS, VARS, CNT, gnw, gnb,
                                             (float*)d_out, 16);
    }
}